// Round 2
// baseline (1515.906 us; speedup 1.0000x reference)
//
#include <hip/hip_runtime.h>

// x: (B=16, C=256, W=64, P=128) fp32 ; codebooks: (NS=4, K=256, SC=64) fp32
#define NSQ 4
#define KCB 256
#define SCH 64
#define NVEC (16*64*128)              // 131072 vectors per subspace

// ---------------------------------------------------------------------------
// Pass 0: codebook norms, bit-identical fmaf order to the in-loop version.
// Result parked in d_out[0..1023] (pass2 later overwrites all of d_out).
// ---------------------------------------------------------------------------
__global__ void pq_norms(const float* __restrict__ cb, float* __restrict__ cn)
{
    const int s = blockIdx.x, k = threadIdx.x;
    const float* row = cb + (size_t)(s * KCB + k) * SCH;
    float n = 0.f;
#pragma unroll
    for (int j4 = 0; j4 < 16; ++j4) {
        float4 v = *(const float4*)(row + j4 * 4);
        n = fmaf(v.x, v.x, n); n = fmaf(v.y, v.y, n);
        n = fmaf(v.z, v.z, n); n = fmaf(v.w, v.w, n);
    }
    cn[s * KCB + k] = n;
}

// ---------------------------------------------------------------------------
// Pass 1: argmin_k ( ||cb[s,k]||^2 - 2 * x_n . cb[s,k] ) over k=0..255.
// 512 threads, 64 KiB LDS -> 2 blocks/CU, 16 waves/CU.
// Thread = (tk 0..15, tn 0..31): 4 n x 16 k fragment, 64 FMA per j.
// ---------------------------------------------------------------------------
__global__ __launch_bounds__(512, 4) void pq_pass1(const float* __restrict__ x,
                                                   const float* __restrict__ cb,
                                                   const float* __restrict__ cnorm,
                                                   int* __restrict__ idx_out)
{
    __shared__ float cbt[64][256];          // 64 KiB
    const int tid = threadIdx.x;
    const int s   = blockIdx.x >> 7;
    const int blk = blockIdx.x & 127;
    const int tk  = tid & 15;
    const int tn  = tid >> 4;               // 0..31
    const int swz = ((tk ^ (tk >> 2)) & 3) << 2;

    if (tid < 256) {                        // stage codebook, swizzled
        const int k    = tid;
        const int tks  = k >> 4;
        const int szs  = ((tks ^ (tks >> 2)) & 3) << 2;
        const int col  = (k & ~15) | ((k & 15) ^ szs);
        const float* row = cb + (size_t)(s * KCB + k) * SCH;
#pragma unroll
        for (int j4 = 0; j4 < 16; ++j4) {
            float4 v = *(const float4*)(row + j4 * 4);
            cbt[j4*4 + 0][col] = v.x;
            cbt[j4*4 + 1][col] = v.y;
            cbt[j4*4 + 2][col] = v.z;
            cbt[j4*4 + 3][col] = v.w;
        }
    }
    __syncthreads();

    const int cb0 = (tk << 4) | (0  ^ swz);
    const int cb1 = (tk << 4) | (4  ^ swz);
    const int cb2 = (tk << 4) | (8  ^ swz);
    const int cb3 = (tk << 4) | (12 ^ swz);
    const float* cnp = cnorm + s * KCB + (tk << 4);

    // first x fragment for tile 0 (prefetch rotation primed here)
    int n_base = blk * 1024;
    const float* xp = x + ((size_t)(((n_base >> 13) * 256 + s * 64) * 64 +
                                    ((n_base >> 7) & 63))) * 128 + 4 * tn;
    float4 xv = *(const float4*)xp;

    for (int t = 0; t < 8; ++t) {
        float acc[4][16];
#pragma unroll
        for (int nn = 0; nn < 4; ++nn)
#pragma unroll
            for (int kk = 0; kk < 16; ++kk) acc[nn][kk] = 0.f;

#pragma unroll 2
        for (int j = 0; j < 63; ++j) {
            float4 xn = *(const float4*)(xp + (size_t)(j + 1) * 8192);
            float c[16];
            {
                float4 t0 = *(const float4*)&cbt[j][cb0];
                float4 t1 = *(const float4*)&cbt[j][cb1];
                float4 t2 = *(const float4*)&cbt[j][cb2];
                float4 t3 = *(const float4*)&cbt[j][cb3];
                c[0]=t0.x; c[1]=t0.y; c[2]=t0.z; c[3]=t0.w;
                c[4]=t1.x; c[5]=t1.y; c[6]=t1.z; c[7]=t1.w;
                c[8]=t2.x; c[9]=t2.y; c[10]=t2.z; c[11]=t2.w;
                c[12]=t3.x; c[13]=t3.y; c[14]=t3.z; c[15]=t3.w;
            }
#pragma unroll
            for (int kk = 0; kk < 16; ++kk) {
                acc[0][kk] = fmaf(xv.x, c[kk], acc[0][kk]);
                acc[1][kk] = fmaf(xv.y, c[kk], acc[1][kk]);
                acc[2][kk] = fmaf(xv.z, c[kk], acc[2][kk]);
                acc[3][kk] = fmaf(xv.w, c[kk], acc[3][kk]);
            }
            xv = xn;
        }
        // prefetch first fragment of next tile, then finish j=63
        {
            const int nb2 = blk * 1024 + (t < 7 ? (t + 1) : t) * 128;
            const float* xp2 = x + ((size_t)(((nb2 >> 13) * 256 + s * 64) * 64 +
                                             ((nb2 >> 7) & 63))) * 128 + 4 * tn;
            float4 xnext = *(const float4*)xp2;

            float c[16];
            {
                float4 t0 = *(const float4*)&cbt[63][cb0];
                float4 t1 = *(const float4*)&cbt[63][cb1];
                float4 t2 = *(const float4*)&cbt[63][cb2];
                float4 t3 = *(const float4*)&cbt[63][cb3];
                c[0]=t0.x; c[1]=t0.y; c[2]=t0.z; c[3]=t0.w;
                c[4]=t1.x; c[5]=t1.y; c[6]=t1.z; c[7]=t1.w;
                c[8]=t2.x; c[9]=t2.y; c[10]=t2.z; c[11]=t2.w;
                c[12]=t3.x; c[13]=t3.y; c[14]=t3.z; c[15]=t3.w;
            }
#pragma unroll
            for (int kk = 0; kk < 16; ++kk) {
                acc[0][kk] = fmaf(xv.x, c[kk], acc[0][kk]);
                acc[1][kk] = fmaf(xv.y, c[kk], acc[1][kk]);
                acc[2][kk] = fmaf(xv.z, c[kk], acc[2][kk]);
                acc[3][kk] = fmaf(xv.w, c[kk], acc[3][kk]);
            }
            xv = xnext;
            xp = xp2;
        }

        // per-thread argmin over its 16 k (first-index tie-break)
        float best[4] = {3.4e38f, 3.4e38f, 3.4e38f, 3.4e38f};
        int   bidx[4] = {0, 0, 0, 0};
#pragma unroll
        for (int kk = 0; kk < 16; ++kk) {
            const float cn = cnp[kk];
            const int k = (tk << 4) + kk;
#pragma unroll
            for (int nn = 0; nn < 4; ++nn) {
                float d = fmaf(-2.f, acc[nn][kk], cn);
                bool better = (d < best[nn]);
                best[nn] = better ? d : best[nn];
                bidx[nn] = better ? k : bidx[nn];
            }
        }
        // reduce across the 16 tk lanes (same wave)
#pragma unroll
        for (int m = 8; m; m >>= 1) {
#pragma unroll
            for (int nn = 0; nn < 4; ++nn) {
                float ob = __shfl_xor(best[nn], m, 64);
                int   oi = __shfl_xor(bidx[nn], m, 64);
                bool take = (ob < best[nn]) || (ob == best[nn] && oi < bidx[nn]);
                best[nn] = take ? ob : best[nn];
                bidx[nn] = take ? oi : bidx[nn];
            }
        }
        if (tk == 0) {
            int4 r; r.x = bidx[0]; r.y = bidx[1]; r.z = bidx[2]; r.w = bidx[3];
            *(int4*)(idx_out + (size_t)s * NVEC + n_base + 4 * tn) = r;
        }
        n_base += 128;
    }
}

// ---------------------------------------------------------------------------
// Pass 2: out[b,c,w,p] = cb[s, idx[s, b*8192 + p*64 + w], c&63],  s = c>>6
// Block = (b, s, j-half, p-half). idx tile L[w][p] (stride 65: conflict-free),
// half codebook cbs[k][jj] (stride 33: gather banks (k+cc)%32, random).
// ---------------------------------------------------------------------------
__global__ __launch_bounds__(512) void pq_pass2(const float* __restrict__ cb,
                                                const int* __restrict__ idx,
                                                float* __restrict__ out)
{
    __shared__ int   L[64][65];        // 16.6 KiB
    __shared__ float cbs[256][33];     // 33.8 KiB
    const int tid = threadIdx.x;
    const int bid = blockIdx.x;
    const int ph  = bid & 1;           // p half
    const int jh  = (bid >> 1) & 1;    // j half
    const int s   = (bid >> 2) & 3;
    const int b   = bid >> 4;
    const int p0  = ph * 64;
    const int j0  = jh * 32;

    // stage idx tile (coalesced): t = (p-p0)*64 + w
    const int* ip = idx + (size_t)s * NVEC + b * 8192 + p0 * 64;
#pragma unroll
    for (int it = 0; it < 8; ++it) {
        int t = it * 512 + tid;
        L[t & 63][t >> 6] = ip[t];
    }
    // stage codebook half (coalesced float4): 256 k x 32 jj
    const float* cp = cb + (size_t)s * (KCB * SCH) + j0;
#pragma unroll
    for (int it = 0; it < 4; ++it) {
        int t = it * 512 + tid;        // 2048 float4 chunks
        int k = t >> 3, jj4 = (t & 7) * 4;
        float4 v = *(const float4*)(cp + (size_t)k * SCH + jj4);
        cbs[k][jj4 + 0] = v.x; cbs[k][jj4 + 1] = v.y;
        cbs[k][jj4 + 2] = v.z; cbs[k][jj4 + 3] = v.w;
    }
    __syncthreads();

    for (int cc = 0; cc < 32; ++cc) {
        const int c = s * 64 + j0 + cc;
        float* op = out + ((size_t)(b * 256 + c) * 64) * 128 + p0;
#pragma unroll
        for (int q = 0; q < 2; ++q) {
            int ch = q * 512 + tid;    // w = ch>>4, p-chunk = (ch&15)*4
            int w  = ch >> 4, pp = (ch & 15) * 4;
            float4 v;
            v.x = cbs[L[w][pp + 0]][cc];
            v.y = cbs[L[w][pp + 1]][cc];
            v.z = cbs[L[w][pp + 2]][cc];
            v.w = cbs[L[w][pp + 3]][cc];
            *(float4*)(op + (size_t)w * 128 + pp) = v;
        }
    }
}

extern "C" void kernel_launch(void* const* d_in, const int* in_sizes, int n_in,
                              void* d_out, int out_size, void* d_ws, size_t ws_size,
                              hipStream_t stream) {
    (void)in_sizes; (void)n_in; (void)out_size; (void)ws_size;
    const float* x   = (const float*)d_in[0];
    const float* cbk = (const float*)d_in[1];
    float*       out = (float*)d_out;
    int*         idx = (int*)d_ws;            // 2 MiB scratch
    float*       cnrm = (float*)d_out;        // parked in d_out; pass2 overwrites

    pq_norms<<<NSQ, KCB, 0, stream>>>(cbk, cnrm);
    pq_pass1<<<NSQ * 128, 512, 0, stream>>>(x, cbk, cnrm, idx);
    pq_pass2<<<16 * NSQ * 2 * 2, 512, 0, stream>>>(cbk, idx, out);
}

// Round 3
// 545.338 us; speedup vs baseline: 2.7798x; 2.7798x over previous
//
#include <hip/hip_runtime.h>

// x: (B=16, C=256, W=64, P=128) fp32 ; codebooks: (NS=4, K=256, SC=64) fp32
#define NSQ 4
#define KCB 256
#define SCH 64
#define NVEC (16*64*128)              // 131072 vectors per subspace

// ---------------------------------------------------------------------------
// Pass 0: codebook norms, bit-identical fmaf order to pass1's epilogue use.
// Result parked in d_out[0..1023] (pass2 later overwrites all of d_out).
// ---------------------------------------------------------------------------
__global__ void pq_norms(const float* __restrict__ cb, float* __restrict__ cn)
{
    const int s = blockIdx.x, k = threadIdx.x;
    const float* row = cb + (size_t)(s * KCB + k) * SCH;
    float n = 0.f;
#pragma unroll
    for (int j4 = 0; j4 < 16; ++j4) {
        float4 v = *(const float4*)(row + j4 * 4);
        n = fmaf(v.x, v.x, n); n = fmaf(v.y, v.y, n);
        n = fmaf(v.z, v.z, n); n = fmaf(v.w, v.w, n);
    }
    cn[s * KCB + k] = n;
}

// ---------------------------------------------------------------------------
// Pass 1: argmin_k ( ||cb[s,k]||^2 - 2 * x_n . cb[s,k] ) over k=0..255.
// 512 threads, 64 KiB LDS -> 2 blocks/CU, 16 waves/CU.
// launch_bounds(512,2): VGPR cap >= 128 under either arg-2 semantics
// (round-2's (512,4) forced 64 VGPR -> 2.4 GB scratch spill).
// Thread = (tk 0..15, tn 0..31): 4 n x 16 k fragment, 64 FMA per j.
// ---------------------------------------------------------------------------
__global__ __launch_bounds__(512, 2) void pq_pass1(const float* __restrict__ x,
                                                   const float* __restrict__ cb,
                                                   const float* __restrict__ cnorm,
                                                   int* __restrict__ idx_out)
{
    __shared__ float cbt[64][256];          // 64 KiB
    const int tid = threadIdx.x;
    const int s   = blockIdx.x >> 7;
    const int blk = blockIdx.x & 127;
    const int tk  = tid & 15;
    const int tn  = tid >> 4;               // 0..31
    const int swz = ((tk ^ (tk >> 2)) & 3) << 2;

    if (tid < 256) {                        // stage codebook, swizzled
        const int k    = tid;
        const int tks  = k >> 4;
        const int szs  = ((tks ^ (tks >> 2)) & 3) << 2;
        const int col  = (k & ~15) | ((k & 15) ^ szs);
        const float* row = cb + (size_t)(s * KCB + k) * SCH;
#pragma unroll
        for (int j4 = 0; j4 < 16; ++j4) {
            float4 v = *(const float4*)(row + j4 * 4);
            cbt[j4*4 + 0][col] = v.x;
            cbt[j4*4 + 1][col] = v.y;
            cbt[j4*4 + 2][col] = v.z;
            cbt[j4*4 + 3][col] = v.w;
        }
    }
    __syncthreads();

    const int cb0 = (tk << 4) | (0  ^ swz);
    const int cb1 = (tk << 4) | (4  ^ swz);
    const int cb2 = (tk << 4) | (8  ^ swz);
    const int cb3 = (tk << 4) | (12 ^ swz);
    const float* cnp = cnorm + s * KCB + (tk << 4);

    // first x fragment for tile 0 (prefetch rotation primed here)
    int n_base = blk * 1024;
    const float* xp = x + ((size_t)(((n_base >> 13) * 256 + s * 64) * 64 +
                                    ((n_base >> 7) & 63))) * 128 + 4 * tn;
    float4 xv = *(const float4*)xp;

    for (int t = 0; t < 8; ++t) {
        float acc[4][16];
#pragma unroll
        for (int nn = 0; nn < 4; ++nn)
#pragma unroll
            for (int kk = 0; kk < 16; ++kk) acc[nn][kk] = 0.f;

#pragma unroll 2
        for (int j = 0; j < 63; ++j) {
            float4 xn = *(const float4*)(xp + (size_t)(j + 1) * 8192);
            float c[16];
            {
                float4 t0 = *(const float4*)&cbt[j][cb0];
                float4 t1 = *(const float4*)&cbt[j][cb1];
                float4 t2 = *(const float4*)&cbt[j][cb2];
                float4 t3 = *(const float4*)&cbt[j][cb3];
                c[0]=t0.x; c[1]=t0.y; c[2]=t0.z; c[3]=t0.w;
                c[4]=t1.x; c[5]=t1.y; c[6]=t1.z; c[7]=t1.w;
                c[8]=t2.x; c[9]=t2.y; c[10]=t2.z; c[11]=t2.w;
                c[12]=t3.x; c[13]=t3.y; c[14]=t3.z; c[15]=t3.w;
            }
#pragma unroll
            for (int kk = 0; kk < 16; ++kk) {
                acc[0][kk] = fmaf(xv.x, c[kk], acc[0][kk]);
                acc[1][kk] = fmaf(xv.y, c[kk], acc[1][kk]);
                acc[2][kk] = fmaf(xv.z, c[kk], acc[2][kk]);
                acc[3][kk] = fmaf(xv.w, c[kk], acc[3][kk]);
            }
            xv = xn;
        }
        // prefetch first fragment of next tile, then finish j=63
        {
            const int nb2 = blk * 1024 + (t < 7 ? (t + 1) : t) * 128;
            const float* xp2 = x + ((size_t)(((nb2 >> 13) * 256 + s * 64) * 64 +
                                             ((nb2 >> 7) & 63))) * 128 + 4 * tn;
            float4 xnext = *(const float4*)xp2;

            float c[16];
            {
                float4 t0 = *(const float4*)&cbt[63][cb0];
                float4 t1 = *(const float4*)&cbt[63][cb1];
                float4 t2 = *(const float4*)&cbt[63][cb2];
                float4 t3 = *(const float4*)&cbt[63][cb3];
                c[0]=t0.x; c[1]=t0.y; c[2]=t0.z; c[3]=t0.w;
                c[4]=t1.x; c[5]=t1.y; c[6]=t1.z; c[7]=t1.w;
                c[8]=t2.x; c[9]=t2.y; c[10]=t2.z; c[11]=t2.w;
                c[12]=t3.x; c[13]=t3.y; c[14]=t3.z; c[15]=t3.w;
            }
#pragma unroll
            for (int kk = 0; kk < 16; ++kk) {
                acc[0][kk] = fmaf(xv.x, c[kk], acc[0][kk]);
                acc[1][kk] = fmaf(xv.y, c[kk], acc[1][kk]);
                acc[2][kk] = fmaf(xv.z, c[kk], acc[2][kk]);
                acc[3][kk] = fmaf(xv.w, c[kk], acc[3][kk]);
            }
            xv = xnext;
            xp = xp2;
        }

        // per-thread argmin over its 16 k (first-index tie-break)
        float best[4] = {3.4e38f, 3.4e38f, 3.4e38f, 3.4e38f};
        int   bidx[4] = {0, 0, 0, 0};
#pragma unroll
        for (int kk = 0; kk < 16; ++kk) {
            const float cn = cnp[kk];
            const int k = (tk << 4) + kk;
#pragma unroll
            for (int nn = 0; nn < 4; ++nn) {
                float d = fmaf(-2.f, acc[nn][kk], cn);
                bool better = (d < best[nn]);
                best[nn] = better ? d : best[nn];
                bidx[nn] = better ? k : bidx[nn];
            }
        }
        // reduce across the 16 tk lanes (same wave)
#pragma unroll
        for (int m = 8; m; m >>= 1) {
#pragma unroll
            for (int nn = 0; nn < 4; ++nn) {
                float ob = __shfl_xor(best[nn], m, 64);
                int   oi = __shfl_xor(bidx[nn], m, 64);
                bool take = (ob < best[nn]) || (ob == best[nn] && oi < bidx[nn]);
                best[nn] = take ? ob : best[nn];
                bidx[nn] = take ? oi : bidx[nn];
            }
        }
        if (tk == 0) {
            int4 r; r.x = bidx[0]; r.y = bidx[1]; r.z = bidx[2]; r.w = bidx[3];
            *(int4*)(idx_out + (size_t)s * NVEC + n_base + 4 * tn) = r;
        }
        n_base += 128;
    }
}

// ---------------------------------------------------------------------------
// Pass 2: out[b,c,w,p] = cb[s, idx[s, b*8192 + p*64 + w], c&63],  s = c>>6
// Block = (b, s, p-half, j-group-of-8): 1024 blocks x 256 thr, 25.8 KiB LDS
// -> 4 blocks/CU resident. idx tile L[w][p] stride 65 (conflict-free both
// sides); codebook cbs[k][jj] stride 9 (staging 2-way; gather ~random banks).
// Each thread preloads its 16 k-values once, reuses across 8 channels.
// ---------------------------------------------------------------------------
__global__ __launch_bounds__(256) void pq_pass2(const float* __restrict__ cb,
                                                const int* __restrict__ idx,
                                                float* __restrict__ out)
{
    __shared__ int   L[64][65];        // 16.6 KiB
    __shared__ float cbs[256][9];      // 9.2 KiB
    const int tid = threadIdx.x;
    const int bid = blockIdx.x;
    const int jq  = bid & 7;           // j group (8 channels)
    const int ph  = (bid >> 3) & 1;    // p half
    const int s   = (bid >> 4) & 3;
    const int b   = bid >> 6;
    const int p0  = ph * 64;
    const int j0  = jq * 8;

    // stage idx tile (coalesced): g = (p-p0)*64 + w
    const int* ip = idx + (size_t)s * NVEC + b * 8192 + p0 * 64;
#pragma unroll
    for (int it = 0; it < 16; ++it) {
        int g = it * 256 + tid;
        L[g & 63][g >> 6] = ip[g];
    }
    // stage 8-wide codebook slice: 256 k x 8 jj
    const float* cp = cb + (size_t)s * (KCB * SCH) + j0;
#pragma unroll
    for (int it = 0; it < 2; ++it) {
        int t = it * 256 + tid;        // 512 float4 chunks
        int k = t >> 1, jj4 = (t & 1) * 4;
        float4 v = *(const float4*)(cp + (size_t)k * SCH + jj4);
        cbs[k][jj4 + 0] = v.x; cbs[k][jj4 + 1] = v.y;
        cbs[k][jj4 + 2] = v.z; cbs[k][jj4 + 3] = v.w;
    }
    __syncthreads();

    // preload this thread's 16 k-values (4 float4-positions), reuse for 8 cc
    int kv[4][4];
#pragma unroll
    for (int q = 0; q < 4; ++q) {
        int ch = q * 256 + tid;        // w = ch>>4 (0..63), pp = (ch&15)*4
        int w  = ch >> 4, pp = (ch & 15) * 4;
#pragma unroll
        for (int e = 0; e < 4; ++e) kv[q][e] = L[w][pp + e];
    }

#pragma unroll
    for (int cc = 0; cc < 8; ++cc) {
        const int c = s * 64 + j0 + cc;
        float* op = out + ((size_t)(b * 256 + c) * 64) * 128 + p0;
#pragma unroll
        for (int q = 0; q < 4; ++q) {
            int ch = q * 256 + tid;
            int w  = ch >> 4, pp = (ch & 15) * 4;
            float4 v;
            v.x = cbs[kv[q][0]][cc];
            v.y = cbs[kv[q][1]][cc];
            v.z = cbs[kv[q][2]][cc];
            v.w = cbs[kv[q][3]][cc];
            *(float4*)(op + (size_t)w * 128 + pp) = v;
        }
    }
}

extern "C" void kernel_launch(void* const* d_in, const int* in_sizes, int n_in,
                              void* d_out, int out_size, void* d_ws, size_t ws_size,
                              hipStream_t stream) {
    (void)in_sizes; (void)n_in; (void)out_size; (void)ws_size;
    const float* x   = (const float*)d_in[0];
    const float* cbk = (const float*)d_in[1];
    float*       out = (float*)d_out;
    int*         idx = (int*)d_ws;            // 2 MiB scratch
    float*       cnrm = (float*)d_out;        // parked in d_out; pass2 overwrites

    pq_norms<<<NSQ, KCB, 0, stream>>>(cbk, cnrm);
    pq_pass1<<<NSQ * 128, 512, 0, stream>>>(x, cbk, cnrm, idx);
    pq_pass2<<<16 * NSQ * 2 * 8, 256, 0, stream>>>(cbk, idx, out);
}